// Round 6
// baseline (368.307 us; speedup 1.0000x reference)
//
#include <hip/hip_runtime.h>
#include <math.h>

#define NT   256
#define N2   2048
#define KTOP 64
#define BB   32
#define LL   4096
#define CC   128
#define PD(i)  ((i) + ((i) >> 5))   // data padding
#define PDT(i) ((i) + ((i) >> 3))   // twiddle-table padding
#define RSQ2 0.70710678118654752f
#define E1C  0.99999882345170188f   // cos(pi/2048)
#define E1S  (-0.00153398018628477f) // sin(-pi/2048)

union USh {
    float2 zc[2112];    // FFT working buffer (fwd fp32 / inverse fp32), 16896 B
    float  keys[2304];  // topk keys overlay
};

__global__ __launch_bounds__(NT, 8)
void fourier_topk_kernel(const float* __restrict__ x, float* __restrict__ out) {
    __shared__ USh u;
    __shared__ float2 T256[288];    // e^{-i pi k/1024}, k<256 (PDT-indexed)
    __shared__ float2 G4s[4];       // e^{-i pi g/4}
    __shared__ unsigned bc_prefix;
    __shared__ int redL[4];
    __shared__ int nbL;
    __shared__ int kbL[48];
    __shared__ double eampL[48];
    __shared__ double dredL[8];
    __shared__ unsigned long long maskL;

    const int tid  = threadIdx.x;
    const int lane = tid & 63;
    const int w    = tid >> 6;

    // XCD-aware swizzle: 16 consecutive channels stay on one XCD
    int d = blockIdx.x;
    int xcd = d & 7, slot = d >> 3;
    int cid = xcd * 32 + (slot >> 4);
    int within = slot & 15;
    int b = cid >> 3;
    int c = ((cid & 7) << 4) + within;

    const float* xp = x + (size_t)b * LL * CC + c;

    // ---- tables
    { float s, cc; sincospif(-(float)tid / 1024.0f, &s, &cc); T256[PDT(tid)] = make_float2(cc, s); }
    if (tid < 4) { float s, cc; sincospif(-(float)tid / 4.0f, &s, &cc); G4s[tid] = make_float2(cc, s); }
    if (tid == 0) nbL = 0;

    // ---- load real series packed: z[m] = x[2m] + i*x[2m+1]
    #pragma unroll
    for (int i = 0; i < 8; ++i) {
        int m = tid + NT * i;
        u.zc[PD(m)] = make_float2(xp[(size_t)(2 * m) * CC], xp[(size_t)(2 * m + 1) * CC]);
    }
    __syncthreads();

    // ---- forward fp32 radix-2^2 DIF: 5 double-stages + final radix-2
    #pragma unroll
    for (int LH = 10; LH >= 2; LH -= 2) {
        const int h = 1 << LH, q = h >> 1;
        #pragma unroll
        for (int it = 0; it < 2; ++it) {
            int bf  = tid + NT * it;
            int j   = bf & (q - 1);
            int blk = bf >> (LH - 1);
            int a   = (blk << (LH + 1)) + j;
            float2 x0 = u.zc[PD(a)],     x1 = u.zc[PD(a + q)];
            float2 x2 = u.zc[PD(a + h)], x3 = u.zc[PD(a + h + q)];
            int e1 = j << (10 - LH);            // < 512
            float2 t = T256[PDT(e1 & 255)];
            float wc, ws;
            if (e1 >> 8) { wc = (t.x + t.y) * RSQ2; ws = (t.y - t.x) * RSQ2; }  // *e^{-i pi/4}
            else         { wc = t.x; ws = t.y; }
            float w2c = wc * wc - ws * ws, w2s = 2.f * wc * ws;                 // W1^2
            float u0r = x0.x + x2.x, u0i = x0.y + x2.y;
            float d0r = x0.x - x2.x, d0i = x0.y - x2.y;
            float u1r = x1.x + x3.x, u1i = x1.y + x3.y;
            float d1r = x1.x - x3.x, d1i = x1.y - x3.y;
            float v0r = d0r * wc - d0i * ws,  v0i = d0r * ws + d0i * wc;        // d0*W1
            float v1r = d1r * ws + d1i * wc,  v1i = d1i * ws - d1r * wc;        // d1*W1*(-i)
            float s0r = u0r + u1r, s0i = u0i + u1i;
            float e0r = u0r - u1r, e0i = u0i - u1i;
            float s1r = v0r + v1r, s1i = v0i + v1i;
            float e1r = v0r - v1r, e1i = v0i - v1i;
            u.zc[PD(a)]         = make_float2(s0r, s0i);
            u.zc[PD(a + q)]     = make_float2(e0r * w2c - e0i * w2s, e0r * w2s + e0i * w2c);
            u.zc[PD(a + h)]     = make_float2(s1r, s1i);
            u.zc[PD(a + h + q)] = make_float2(e1r * w2c - e1i * w2s, e1r * w2s + e1i * w2c);
        }
        __syncthreads();
    }
    #pragma unroll
    for (int it = 0; it < 4; ++it) {            // final radix-2, W=1
        int a = 2 * (tid + NT * it);
        float2 x0 = u.zc[PD(a)], x1 = u.zc[PD(a + 1)];
        u.zc[PD(a)]     = make_float2(x0.x + x1.x, x0.y + x1.y);
        u.zc[PD(a + 1)] = make_float2(x0.x - x1.x, x0.y - x1.y);
    }
    __syncthreads();

    // ---- untwiddle to rfft bins (registers)
    unsigned ku[9]; float fxr[9], fxi[9];
    #pragma unroll
    for (int q9 = 0; q9 < 9; ++q9) {
        int k = tid + NT * q9;
        const bool valid = (q9 < 8) || (tid == 0);
        ku[q9] = 0u; fxr[q9] = 0.f; fxi[q9] = 0.f;
        if (valid) {
            int k1 = k & (N2 - 1), k2 = (N2 - k1) & (N2 - 1);
            int pa = __brev((unsigned)k1) >> 21, pb = __brev((unsigned)k2) >> 21;
            float2 A = u.zc[PD(pa)], Bz = u.zc[PD(pb)];
            float Er = 0.5f * (A.x + Bz.x), Ei = 0.5f * (A.y - Bz.y);
            float Or = 0.5f * (A.y + Bz.y), Oi = 0.5f * (Bz.x - A.x);
            float Xr, Xi;
            if (k == N2) { Xr = Er - Or; Xi = 0.f; }
            else {
                int m = k >> 1, r = k & 1;
                float2 t = T256[PDT(m & 255)], g = G4s[m >> 8];
                float uc = t.x * g.x - t.y * g.y, us = t.x * g.y + t.y * g.x;   // e^{-i pi m/1024}
                if (r) {
                    float nc = uc * E1C - us * E1S;
                    us = uc * E1S + us * E1C; uc = nc;
                }
                Xr = Er + uc * Or - us * Oi;
                Xi = Ei + uc * Oi + us * Or;
            }
            fxr[q9] = Xr; fxi[q9] = Xi;
            ku[q9] = __float_as_uint(Xr * Xr + Xi * Xi);
        }
    }
    __syncthreads();                       // zc reads done

    // ---- stage keys into LDS; single-wave rank-64 bit descent
    #pragma unroll
    for (int q9 = 0; q9 < 9; ++q9) u.keys[tid + NT * q9] = __uint_as_float(ku[q9]);
    __syncthreads();

    if (tid < 64) {
        unsigned lk[36];
        #pragma unroll
        for (int i = 0; i < 36; ++i) lk[i] = __float_as_uint(u.keys[tid + 64 * i]);
        unsigned prefix = 0;
        for (int bit = 30; bit >= 0; --bit) {
            unsigned cand = prefix | (1u << bit);
            int cnt = 0;
            #pragma unroll
            for (int i = 0; i < 36; ++i) cnt += (lk[i] >= cand) ? 1 : 0;
            for (int off = 1; off < 64; off <<= 1) cnt += __shfl_xor(cnt, off);
            if (cnt >= KTOP) prefix = cand;
        }
        if (tid == 0) bc_prefix = prefix;
    }
    __syncthreads();

    // ---- classification with safety margin; exact fp64 refinement if ambiguous
    const float tf = __uint_as_float(bc_prefix);
    const float hi = tf * (1.0f + 1e-4f);
    const float lo = tf * (1.0f - 1e-4f);

    int nsure = 0;
    int bsl[9]; bool bfl[9];
    #pragma unroll
    for (int q9 = 0; q9 < 9; ++q9) {
        const bool valid = (q9 < 8) || (tid == 0);
        float a2 = __uint_as_float(ku[q9]);
        bool su = valid && (a2 > hi);
        bool bd = valid && !su && (a2 >= lo);
        nsure += su ? 1 : 0;
        bfl[q9] = bd; bsl[q9] = 63;
        if (bd) {
            int s2 = atomicAdd(&nbL, 1);
            if (s2 < 48) { kbL[s2] = tid + NT * q9; bsl[q9] = s2; }
        }
    }
    for (int off = 1; off < 64; off <<= 1) nsure += __shfl_xor(nsure, off);
    if (lane == 0) redL[w] = nsure;
    __syncthreads();
    const int n_sure = redL[0] + redL[1] + redL[2] + redL[3];
    const int need   = KTOP - n_sure;
    const int nb     = min(nbL, 48);

    unsigned long long selmask;
    if (nb > need) {
        // exact fp64 DFT for each borderline bin (cooperative, rare path)
        for (int i = 0; i < nb; ++i) {
            int k = kbL[i];
            double sr = 0.0, si = 0.0;
            #pragma unroll
            for (int j = 0; j < 16; ++j) {
                int t = tid + NT * j;
                int m = (k * t) & (2 * N2 - 1);
                double sn, cs; sincospi(-(double)m / 2048.0, &sn, &cs);
                double xv = (double)xp[(size_t)t * CC];
                sr = fma(xv, cs, sr); si = fma(xv, sn, si);
            }
            for (int off = 1; off < 64; off <<= 1) {
                sr += __shfl_xor(sr, off); si += __shfl_xor(si, off);
            }
            if (lane == 0) { dredL[2 * w] = sr; dredL[2 * w + 1] = si; }
            __syncthreads();
            if (tid == 0) {
                double R = dredL[0] + dredL[2] + dredL[4] + dredL[6];
                double I = dredL[1] + dredL[3] + dredL[5] + dredL[7];
                eampL[i] = R * R + I * I;
            }
            __syncthreads();
        }
        if (tid == 0) {          // top-`need` by exact key, ties -> lowest bin
            unsigned long long m = 0;
            for (int s2 = 0; s2 < need; ++s2) {
                int best = -1, bk = 1 << 30; double bv = -1.0;
                for (int i = 0; i < nb; ++i) {
                    if ((m >> i) & 1ull) continue;
                    double v = eampL[i]; int k = kbL[i];
                    if (v > bv || (v == bv && k < bk)) { bv = v; bk = k; best = i; }
                }
                m |= 1ull << best;
            }
            maskL = m;
        }
        __syncthreads();
        selmask = maskL;
    } else {
        selmask = ~0ull;     // keep all borderline
    }

    bool kp[9];
    #pragma unroll
    for (int q9 = 0; q9 < 9; ++q9) {
        const bool valid = (q9 < 8) || (tid == 0);
        float a2 = __uint_as_float(ku[q9]);
        kp[q9] = (valid && a2 > hi) || (bfl[q9] && ((selmask >> bsl[q9]) & 1ull));
    }
    __syncthreads();                       // keys dead; zc region reusable

    // ---- zero sparse spectrum
    #pragma unroll
    for (int i = 0; i < 9; ++i) {
        int idx = tid + NT * i;
        if (idx < 2112) u.zc[idx] = make_float2(0.f, 0.f);
    }
    __syncthreads();

    // ---- scatter kept bins into packed half-spectrum, bit-reversed positions
    float* zf = (float*)u.zc;
    #pragma unroll
    for (int q9 = 0; q9 < 9; ++q9) {
        if (kp[q9]) {
            int k = tid + NT * q9;
            float a = fxr[q9], bq = fxi[q9];
            float sth, cth; sincospif((float)k * (1.0f / 2048.0f), &sth, &cth);
            float Px = 0.5f * (1.f - sth), Py = 0.5f * cth;
            if (k < N2) {
                int p = PD((int)(__brev((unsigned)k) >> 21));
                atomicAdd(&zf[2 * p],     a * Px - bq * Py);
                atomicAdd(&zf[2 * p + 1], a * Py + bq * Px);
            }
            if (k > 0) {
                int m2 = (N2 - k) & (N2 - 1);
                int p = PD((int)(__brev((unsigned)m2) >> 21));
                float Qx = 1.f - Px, Qy = Py;
                atomicAdd(&zf[2 * p],     a * Qx + bq * Qy);
                atomicAdd(&zf[2 * p + 1], a * Qy - bq * Qx);
            }
        }
    }
    __syncthreads();

    // ---- inverse fp32 radix-2^2 DIT (bit-reversed in -> natural out)
    #pragma unroll
    for (int LH = 0; LH <= 8; LH += 2) {
        const int h = 1 << LH;
        #pragma unroll
        for (int it = 0; it < 2; ++it) {
            int bf  = tid + NT * it;
            int j   = bf & (h - 1);
            int blk = bf >> LH;
            int a   = (blk << (LH + 2)) + j;
            float2 x0 = u.zc[PD(a)],         x1 = u.zc[PD(a + h)];
            float2 x2 = u.zc[PD(a + 2 * h)], x3 = u.zc[PD(a + 3 * h)];
            int eB = j << (9 - LH);             // < 512
            float2 t = T256[PDT(eB & 255)];
            float cc, ss;
            if (eB >> 8) { cc = (t.x + t.y) * RSQ2; ss = (t.y - t.x) * RSQ2; }
            else         { cc = t.x; ss = t.y; }
            float wbc = cc, wbs = -ss;          // WB = e^{+i...} (conj)
            float wac = wbc * wbc - wbs * wbs, was = 2.f * wbc * wbs;
            float vr = x1.x * wac - x1.y * was, vi = x1.x * was + x1.y * wac;
            float y0r = x0.x + vr, y0i = x0.y + vi, y1r = x0.x - vr, y1i = x0.y - vi;
            float ur = x3.x * wac - x3.y * was, ui = x3.x * was + x3.y * wac;
            float y2r = x2.x + ur, y2i = x2.y + ui, y3r = x2.x - ur, y3i = x2.y - ui;
            float b0r = y2r * wbc - y2i * wbs, b0i = y2r * wbs + y2i * wbc;
            float b1r = -(y3r * wbs) - y3i * wbc, b1i = y3r * wbc - y3i * wbs;  // *(WB*i)
            u.zc[PD(a)]         = make_float2(y0r + b0r, y0i + b0i);
            u.zc[PD(a + 2 * h)] = make_float2(y0r - b0r, y0i - b0i);
            u.zc[PD(a + h)]     = make_float2(y1r + b1r, y1i + b1i);
            u.zc[PD(a + 3 * h)] = make_float2(y1r - b1r, y1i - b1i);
        }
        __syncthreads();
    }
    #pragma unroll
    for (int it = 0; it < 4; ++it) {            // final DIT stage, half=1024
        int j = tid + NT * it;                  // 0..1023
        float2 x0 = u.zc[PD(j)], x1 = u.zc[PD(j + 1024)];
        float2 t = T256[PDT(j & 255)], g = G4s[j >> 8];
        float cc = t.x * g.x - t.y * g.y, ss = t.x * g.y + t.y * g.x;  // e^{-i pi j/1024}
        float wc = cc, ws = -ss;                                        // conj
        float vr = x1.x * wc - x1.y * ws, vi = x1.x * ws + x1.y * wc;
        u.zc[PD(j)]        = make_float2(x0.x + vr, x0.y + vi);
        u.zc[PD(j + 1024)] = make_float2(x0.x - vr, x0.y - vi);
    }
    __syncthreads();

    // ---- unpack + write: x[2m] = Re z[m]/2048, x[2m+1] = Im z[m]/2048
    float* op = out + (size_t)b * LL * CC + c;
    const float inv = 1.0f / 2048.0f;
    #pragma unroll
    for (int i = 0; i < 8; ++i) {
        int m = tid + NT * i;
        float2 z = u.zc[PD(m)];
        op[(size_t)(2 * m)     * CC] = z.x * inv;
        op[(size_t)(2 * m + 1) * CC] = z.y * inv;
    }
}

extern "C" void kernel_launch(void* const* d_in, const int* in_sizes, int n_in,
                              void* d_out, int out_size, void* d_ws, size_t ws_size,
                              hipStream_t stream) {
    (void)in_sizes; (void)n_in; (void)d_ws; (void)ws_size; (void)out_size;
    const float* x = (const float*)d_in[0];
    float* out = (float*)d_out;
    dim3 grid(BB * CC), block(NT);
    hipLaunchKernelGGL(fourier_topk_kernel, grid, block, 0, stream, x, out);
}